// Round 3
// baseline (129.676 us; speedup 1.0000x reference)
//
#include <hip/hip_runtime.h>
#include <hip/hip_bf16.h>

#define NB 8192   // batch
#define ND 512    // feature dim
#define NC 512    // num classes
#define MARGIN_F 1.0f
#define BIGF 3.0e38f

typedef __attribute__((ext_vector_type(8))) short          bf16x8;
typedef __attribute__((ext_vector_type(8))) unsigned short ushort8;
typedef __attribute__((ext_vector_type(4))) float          f32x4;

__device__ __forceinline__ unsigned fkey(float f) {
    unsigned u = __float_as_uint(f);
    unsigned mask = (u & 0x80000000u) ? 0xFFFFFFFFu : 0x80000000u;
    return u ^ mask;
}
__device__ __forceinline__ float finv(unsigned k) {
    unsigned mask = (k & 0x80000000u) ? 0x80000000u : 0xFFFFFFFFu;
    return __uint_as_float(k ^ mask);
}
__device__ __forceinline__ unsigned short f2bf(float f) {
    __hip_bfloat16 h = __float2bfloat16(f);
    return __builtin_bit_cast(unsigned short, h);
}

// -------------------------------------------------------------------------
// k0: centers fp32->bf16 + csq (blocks 0..127, wave per center),
//     histogram + done-counter init (block 128).
// -------------------------------------------------------------------------
__global__ __launch_bounds__(256) void k0_prep(
    const float* __restrict__ centers, const int* __restrict__ targets,
    unsigned short* __restrict__ cenB, float* __restrict__ csq,
    unsigned* __restrict__ counts, unsigned* __restrict__ done)
{
    const int bid = blockIdx.x;
    const int tid = threadIdx.x;

    if (bid == 128) {
        __shared__ unsigned hist[NC];
        for (int i = tid; i < NC; i += 256) hist[i] = 0u;
        __syncthreads();
        for (int i = tid; i < NB; i += 256) atomicAdd(&hist[targets[i]], 1u);
        __syncthreads();
        for (int i = tid; i < NC; i += 256) counts[i] = hist[i];
        if (tid == 0) *done = 0u;
        return;
    }

    const int wave = tid >> 6, lane = tid & 63;
    const int c = bid * 4 + wave;
    const float4* row = (const float4*)&centers[(size_t)c * ND];
    float4 v1 = row[lane];
    float4 v2 = row[lane + 64];
    float s = v1.x*v1.x + v1.y*v1.y + v1.z*v1.z + v1.w*v1.w
            + v2.x*v2.x + v2.y*v2.y + v2.z*v2.z + v2.w*v2.w;

    ushort4 o1, o2;
    o1.x = f2bf(v1.x); o1.y = f2bf(v1.y); o1.z = f2bf(v1.z); o1.w = f2bf(v1.w);
    o2.x = f2bf(v2.x); o2.y = f2bf(v2.y); o2.z = f2bf(v2.z); o2.w = f2bf(v2.w);
    unsigned short* dst = cenB + (size_t)c * ND;
    ((ushort4*)dst)[lane]      = o1;
    ((ushort4*)dst)[lane + 64] = o2;

    #pragma unroll
    for (int off = 32; off > 0; off >>= 1) s += __shfl_down(s, off);
    if (lane == 0) csq[c] = s;
}

// -------------------------------------------------------------------------
// k2: bf16 MFMA GEMM (A fp32 staged+converted in-kernel) + masked-min
//     epilogue + last-block finalize. BM=BN=128, BK=64, 512 threads.
//     LDS tiles padded to stride 72 shorts -> conflict-free b128 frag reads.
//     grid = (4 ctiles, 64 rtiles) = 256 blocks.
// -------------------------------------------------------------------------
__global__ __launch_bounds__(512) void k2_mfma(
    const float* __restrict__ inputs, const unsigned short* __restrict__ cenB,
    const int* __restrict__ targets, const unsigned* __restrict__ counts,
    const float* __restrict__ csq,
    float* __restrict__ partmin, float* __restrict__ apval,
    float* __restrict__ rsq, unsigned* __restrict__ done,
    float* __restrict__ out)
{
    __shared__ __align__(16) unsigned short As[128 * 72];  // stride 72 = pad 8
    __shared__ __align__(16) unsigned short Bs[128 * 72];
    __shared__ int      tgtL[128];
    __shared__ float    csqL[128];
    __shared__ unsigned ldsmin[128];
    __shared__ float    red[16];
    __shared__ int      lastFlag;

    const int tid  = threadIdx.x;
    const int w    = tid >> 6;
    const int lane = tid & 63;
    const int wm   = w >> 2;      // 0..1 : 64-row half
    const int wn   = w & 3;       // 0..3 : 32-col quarter
    const int qd   = lane >> 4;   // quad 0..3
    const int ln   = lane & 15;

    const int rbase = blockIdx.y * 128;
    const int cbase = blockIdx.x * 128;

    if (tid < 128) {
        tgtL[tid]   = targets[rbase + tid];
        const int c = cbase + tid;
        csqL[tid]   = (counts[c] > 0u) ? csq[c] : BIGF;  // empty class never wins min
        ldsmin[tid] = 0xFFFFFFFFu;
    }

    // staging map: thread t -> row t/4, cols (t&3)*16 .. +16 of the BK=64 tile
    const int srow = tid >> 2;          // 0..127
    const int scol = (tid & 3) * 16;    // 0,16,32,48
    const float*          gA = inputs + (size_t)(rbase + srow) * ND + scol;
    const unsigned short* gB = cenB   + (size_t)(cbase + srow) * ND + scol;
    unsigned short* lA = &As[srow * 72 + scol];
    unsigned short* lB = &Bs[srow * 72 + scol];

    const bool do_rsq = (blockIdx.x == 0);
    float rs = 0.0f;

    f32x4 acc[4][2] = {};

    for (int kb = 0; kb < ND; kb += 64) {
        float4  a0 = *(const float4*) (gA + kb + 0);
        float4  a1 = *(const float4*) (gA + kb + 4);
        float4  a2 = *(const float4*) (gA + kb + 8);
        float4  a3 = *(const float4*) (gA + kb + 12);
        ushort8 b0 = *(const ushort8*)(gB + kb + 0);
        ushort8 b1 = *(const ushort8*)(gB + kb + 8);

        if (do_rsq) {
            rs += a0.x*a0.x + a0.y*a0.y + a0.z*a0.z + a0.w*a0.w;
            rs += a1.x*a1.x + a1.y*a1.y + a1.z*a1.z + a1.w*a1.w;
            rs += a2.x*a2.x + a2.y*a2.y + a2.z*a2.z + a2.w*a2.w;
            rs += a3.x*a3.x + a3.y*a3.y + a3.z*a3.z + a3.w*a3.w;
        }

        ushort8 c0, c1;
        c0[0]=f2bf(a0.x); c0[1]=f2bf(a0.y); c0[2]=f2bf(a0.z); c0[3]=f2bf(a0.w);
        c0[4]=f2bf(a1.x); c0[5]=f2bf(a1.y); c0[6]=f2bf(a1.z); c0[7]=f2bf(a1.w);
        c1[0]=f2bf(a2.x); c1[1]=f2bf(a2.y); c1[2]=f2bf(a2.z); c1[3]=f2bf(a2.w);
        c1[4]=f2bf(a3.x); c1[5]=f2bf(a3.y); c1[6]=f2bf(a3.z); c1[7]=f2bf(a3.w);

        __syncthreads();                       // prev iter's frag reads done
        *(ushort8*)lA       = c0;
        *(ushort8*)(lA + 8) = c1;
        *(ushort8*)lB       = b0;
        *(ushort8*)(lB + 8) = b1;
        __syncthreads();                       // tile visible

        #pragma unroll
        for (int ks = 0; ks < 2; ++ks) {
            bf16x8 a[4], b[2];
            #pragma unroll
            for (int i = 0; i < 4; ++i)
                a[i] = *(const bf16x8*)&As[(wm*64 + i*16 + ln)*72 + ks*32 + qd*8];
            #pragma unroll
            for (int j = 0; j < 2; ++j)
                b[j] = *(const bf16x8*)&Bs[(wn*32 + j*16 + ln)*72 + ks*32 + qd*8];
            #pragma unroll
            for (int i = 0; i < 4; ++i)
                #pragma unroll
                for (int j = 0; j < 2; ++j)
                    acc[i][j] = __builtin_amdgcn_mfma_f32_16x16x32_bf16(a[i], b[j], acc[i][j], 0, 0, 0);
        }
    }

    // row sqnorms (ctile-0 blocks only): 4 staging threads per row hold partials
    if (do_rsq) {
        rs += __shfl_xor(rs, 1);
        rs += __shfl_xor(rs, 2);
        if ((tid & 3) == 0) rsq[rbase + srow] = rs;
    }

    // Epilogue. C/D layout: col = lane&15, row = (lane>>4)*4 + reg.
    #pragma unroll
    for (int i = 0; i < 4; ++i) {
        #pragma unroll
        for (int r = 0; r < 4; ++r) {
            const int rlocal = wm * 64 + i * 16 + qd * 4 + r;
            const int grow   = rbase + rlocal;
            const int tr     = tgtL[rlocal];
            float m = BIGF;
            #pragma unroll
            for (int j = 0; j < 2; ++j) {
                const int clocal = wn * 32 + j * 16 + ln;
                const float val = csqL[clocal] - 2.0f * acc[i][j][r];
                if (cbase + clocal == tr) {
                    apval[grow] = val;                 // exactly one writer per row
                } else {
                    m = fminf(m, val);
                }
            }
            #pragma unroll
            for (int off = 1; off < 16; off <<= 1)     // min over 16 cols in-quad
                m = fminf(m, __shfl_xor(m, off));
            if (ln == 0) atomicMin(&ldsmin[rlocal], fkey(m));
        }
    }
    __syncthreads();
    if (tid < 128)
        partmin[(size_t)blockIdx.x * NB + rbase + tid] = finv(ldsmin[tid]);

    // ---- last-done block runs the finalize ----
    __threadfence();
    if (tid == 0) {
        unsigned old = atomicAdd(done, 1u);
        lastFlag = (old == 255u) ? 1 : 0;
    }
    __syncthreads();
    if (!lastFlag) return;
    __threadfence();

    float la = 0.0f, lp = 0.0f;
    for (int rr = tid; rr < NB; rr += 512) {
        float m = fminf(fminf(partmin[rr],        partmin[NB + rr]),
                        fminf(partmin[2*NB + rr], partmin[3*NB + rr]));
        float s  = rsq[rr];
        float an = sqrtf(fmaxf(s + m,         1e-12f));
        float ap = sqrtf(fmaxf(s + apval[rr], 1e-12f));
        la += fmaxf(0.0f, ap - an + MARGIN_F);
        lp += (an > ap) ? 1.0f : 0.0f;
    }
    #pragma unroll
    for (int off = 32; off > 0; off >>= 1) {
        la += __shfl_down(la, off);
        lp += __shfl_down(lp, off);
    }
    if (lane == 0) { red[w] = la; red[8 + w] = lp; }
    __syncthreads();
    if (tid == 0) {
        float A = 0.0f, P = 0.0f;
        #pragma unroll
        for (int i = 0; i < 8; ++i) { A += red[i]; P += red[8 + i]; }
        out[0] = A / (float)NB;
        out[1] = P / (float)NB;
    }
}

extern "C" void kernel_launch(void* const* d_in, const int* in_sizes, int n_in,
                              void* d_out, int out_size, void* d_ws, size_t ws_size,
                              hipStream_t stream) {
    const float* inputs  = (const float*)d_in[0];
    const int*   targets = (const int*)d_in[1];
    const float* centers = (const float*)d_in[2];
    float* out = (float*)d_out;

    // ws layout (bytes):
    char* wp = (char*)d_ws;
    unsigned short* cenB    = (unsigned short*)(wp);            // 512*512*2 = 524288
    float*          csqv    = (float*)(wp + 524288);            // 512*4
    unsigned*       counts  = (unsigned*)(wp + 526336);         // 512*4
    float*          rsq     = (float*)(wp + 528384);            // 8192*4
    float*          apval   = (float*)(wp + 561152);            // 8192*4
    float*          partmin = (float*)(wp + 593920);            // 4*8192*4 = 131072
    unsigned*       done    = (unsigned*)(wp + 724992);         // 4

    k0_prep<<<129, 256, 0, stream>>>(centers, targets, cenB, csqv, counts, done);
    k2_mfma<<<dim3(4, 64), 512, 0, stream>>>(inputs, cenB, targets, counts, csqv,
                                             partmin, apval, rsq, done, out);
}